// Round 1
// baseline (134.438 us; speedup 1.0000x reference)
//
#include <hip/hip_runtime.h>

#define MIN_VAL 1e-8f
#define BIGF    1e10f

constexpr int P     = 256;   // bins per sample (bins input is [N, P+1])
constexpr int BLOCK = 256;
constexpr int CHUNK = 1024;  // targets per block (== 4 * BLOCK)

// ---------------------------------------------------------------------------
// ws layout (d_ws is poisoned 0xAA before every launch -> init every call):
//   [0,   64)  : double ysum[8]        (cham_y numerator per sample)
//   [64,  96)  : unsigned ycnt[8]      (valid-target count per sample)
//   [96, 96+8*256*4) : unsigned minbits[N*P]  (per-bin min dist, uint-ordered)
// ---------------------------------------------------------------------------

__global__ void chamfer_init(double* ysum, unsigned* ycnt, unsigned* minbits,
                             int N) {
    int tid = threadIdx.x;
    unsigned bigbits = __float_as_uint(BIGF);
    for (int i = tid; i < N * P; i += BLOCK) minbits[i] = bigbits;
    if (tid < N) { ysum[tid] = 0.0; ycnt[tid] = 0u; }
}

__global__ void __launch_bounds__(BLOCK)
chamfer_main(const float* __restrict__ bins, const float* __restrict__ tgt,
             int N, int M, int chunksPerSample,
             double* ysum, unsigned* ycnt, unsigned* minbits) {
    const int b   = blockIdx.x;
    const int n   = b / chunksPerSample;
    const int c   = b % chunksPerSample;
    const int m0  = c * CHUNK;
    const int tid = threadIdx.x;

    __shared__ float s_bc[P];
    __shared__ float s_t[CHUNK];
    __shared__ double s_wsum[BLOCK / 64];
    __shared__ unsigned s_wcnt[BLOCK / 64];

    // bin centers for this sample
    const float* bn = bins + (size_t)n * (P + 1);
    if (tid < P) s_bc[tid] = 0.5f * (bn[tid] + bn[tid + 1]);

    // stage target chunk (pad out-of-range with invalid sentinel)
    const float* tp = tgt + (size_t)n * M;
    for (int i = tid; i < CHUNK; i += BLOCK) {
        int m = m0 + i;
        s_t[i] = (m < M) ? tp[m] : -1.0f;  // -1 < MIN_VAL -> invalid
    }
    __syncthreads();

    // ---- phase 1: per-target min over bins (cham_y direction) -------------
    float t0 = s_t[tid];
    float t1 = s_t[tid + 256];
    float t2 = s_t[tid + 512];
    float t3 = s_t[tid + 768];
    float m0f = BIGF, m1f = BIGF, m2f = BIGF, m3f = BIGF;
#pragma unroll 4
    for (int p = 0; p < P; ++p) {
        float bc = s_bc[p];  // broadcast read, conflict-free
        float a0 = bc - t0; m0f = fminf(m0f, a0 * a0);
        float a1 = bc - t1; m1f = fminf(m1f, a1 * a1);
        float a2 = bc - t2; m2f = fminf(m2f, a2 * a2);
        float a3 = bc - t3; m3f = fminf(m3f, a3 * a3);
    }
    double local = 0.0;
    unsigned cl = 0;
    if (t0 >= MIN_VAL) { local += (double)m0f; ++cl; }
    if (t1 >= MIN_VAL) { local += (double)m1f; ++cl; }
    if (t2 >= MIN_VAL) { local += (double)m2f; ++cl; }
    if (t3 >= MIN_VAL) { local += (double)m3f; ++cl; }

    // ---- phase 2: per-bin min over this chunk's targets (cham_x) ----------
    // thread tid owns bin tid (BLOCK == P); running min in one register
    float bc = s_bc[tid];
    float bmin = BIGF;
#pragma unroll 4
    for (int i = 0; i < CHUNK; ++i) {
        float t = s_t[i];  // broadcast read, conflict-free
        float d = bc - t;
        d = d * d;
        d = (t >= MIN_VAL) ? d : BIGF;
        bmin = fminf(bmin, d);
    }
    atomicMin(&minbits[n * P + tid], __float_as_uint(bmin));

    // ---- block-reduce cham_y partials, one atomic pair per block ----------
    for (int off = 32; off > 0; off >>= 1) {
        local += __shfl_down(local, off, 64);
        cl    += __shfl_down(cl, off, 64);
    }
    int wave = tid >> 6, lane = tid & 63;
    if (lane == 0) { s_wsum[wave] = local; s_wcnt[wave] = cl; }
    __syncthreads();
    if (tid == 0) {
        double s = s_wsum[0] + s_wsum[1] + s_wsum[2] + s_wsum[3];
        unsigned cc = s_wcnt[0] + s_wcnt[1] + s_wcnt[2] + s_wcnt[3];
        atomicAdd(&ysum[n], s);
        atomicAdd(&ycnt[n], cc);
    }
}

__global__ void __launch_bounds__(BLOCK)
chamfer_final(const double* __restrict__ ysum, const unsigned* __restrict__ ycnt,
              const unsigned* __restrict__ minbits, float* out, int N) {
    int tid = threadIdx.x;  // one thread per bin
    double acc = 0.0;
    for (int n = 0; n < N; ++n)
        acc += (double)__uint_as_float(minbits[n * P + tid]);
    for (int off = 32; off > 0; off >>= 1) acc += __shfl_down(acc, off, 64);
    __shared__ double w[BLOCK / 64];
    if ((tid & 63) == 0) w[tid >> 6] = acc;
    __syncthreads();
    if (tid == 0) {
        double sx = (w[0] + w[1] + w[2] + w[3]) / (double)P;  // sum_n mean_p
        double sy = 0.0;
        for (int n = 0; n < N; ++n) sy += ysum[n] / (double)ycnt[n];
        out[0] = (float)((sx + sy) / (double)N);
    }
}

extern "C" void kernel_launch(void* const* d_in, const int* in_sizes, int n_in,
                              void* d_out, int out_size, void* d_ws, size_t ws_size,
                              hipStream_t stream) {
    const float* bins = (const float*)d_in[0];
    const float* tgt  = (const float*)d_in[1];
    float* out = (float*)d_out;

    const int N = in_sizes[0] / (P + 1);     // 8
    const int M = in_sizes[1] / N;           // 65536

    char* ws = (char*)d_ws;
    double*   ysum    = (double*)ws;                 // 8 doubles
    unsigned* ycnt    = (unsigned*)(ws + 64);        // 8 uints
    unsigned* minbits = (unsigned*)(ws + 96);        // N*P uints

    const int chunksPerSample = (M + CHUNK - 1) / CHUNK;  // 64
    const int nBlocks = N * chunksPerSample;              // 512

    hipLaunchKernelGGL(chamfer_init, dim3(1), dim3(BLOCK), 0, stream,
                       ysum, ycnt, minbits, N);
    hipLaunchKernelGGL(chamfer_main, dim3(nBlocks), dim3(BLOCK), 0, stream,
                       bins, tgt, N, M, chunksPerSample, ysum, ycnt, minbits);
    hipLaunchKernelGGL(chamfer_final, dim3(1), dim3(BLOCK), 0, stream,
                       ysum, ycnt, minbits, out, N);
}

// Round 2
// 99.044 us; speedup vs baseline: 1.3573x; 1.3573x over previous
//
#include <hip/hip_runtime.h>

#define MIN_VAL 1e-8f
#define BIGF    1e10f

constexpr int P     = 256;   // bins per sample (bins input is [N, P+1])
constexpr int BLOCK = 256;
constexpr int CHUNK = 512;   // targets per block (2 per thread)

// ---------------------------------------------------------------------------
// ws layout (poisoned 0xAA before every launch; init kernel sets it up):
//   [0,4)    : unsigned done
//   [64,128) : double ysum[8]
//   [128,160): unsigned ycnt[8]
//   [192, 192+N*P*4): unsigned minbits[N*P]  (uint-ordered per-bin min d^2)
// ---------------------------------------------------------------------------

__global__ void chamfer_init(unsigned* done, double* ysum, unsigned* ycnt,
                             unsigned* minbits, int N) {
    int tid = threadIdx.x;
    unsigned bigbits = __float_as_uint(BIGF);
    for (int i = tid; i < N * P; i += BLOCK) minbits[i] = bigbits;
    if (tid < N) { ysum[tid] = 0.0; ycnt[tid] = 0u; }
    if (tid == 0) *done = 0u;
}

__global__ void __launch_bounds__(BLOCK)
chamfer_main(const float* __restrict__ bins, const float* __restrict__ tgt,
             int N, int M, unsigned* done, double* ysum, unsigned* ycnt,
             unsigned* minbits, float* out) {
    const int n   = blockIdx.y;
    const int c   = blockIdx.x;
    const int m0  = c * CHUNK;
    const int tid = threadIdx.x;

    __shared__ float4 s_ef4[P / 2];      // {bc^2, -2bc} pairs for 2 bins
    __shared__ float4 s_gh4[CHUNK / 2];  // {-2t, t^2} pairs for 2 targets
    __shared__ double s_wsum[BLOCK / 64];
    __shared__ unsigned s_wcnt[BLOCK / 64];
    __shared__ int s_last;

    // ---- stage bins: thread tid owns bin tid ------------------------------
    const float* bn = bins + (size_t)n * (P + 1);
    float bc = 0.5f * (bn[tid] + bn[tid + 1]);
    ((float2*)s_ef4)[tid] = make_float2(bc * bc, -2.0f * bc);

    // ---- stage targets: thread tid owns targets m0+2tid, m0+2tid+1 --------
    const float* tp = tgt + (size_t)n * M;
    int m = m0 + 2 * tid;
    float t0, t1;
    if (m + 1 < M) {
        float2 tt = *(const float2*)(tp + m);
        t0 = tt.x; t1 = tt.y;
    } else {
        t0 = (m < M) ? tp[m] : -1.0f;
        t1 = -1.0f;
    }
    bool v0 = t0 >= MIN_VAL, v1 = t1 >= MIN_VAL;
    // sentinel for invalid: t'=1e10 -> score ~1e20 dominates any valid score
    float g0 = v0 ? -2.0f * t0 : -2e10f, h0 = v0 ? t0 * t0 : 1e20f;
    float g1 = v1 ? -2.0f * t1 : -2e10f, h1 = v1 ? t1 * t1 : 1e20f;
    s_gh4[tid] = make_float4(g0, h0, g1, h1);
    __syncthreads();

    // ---- phase 1: per-target min over bins (cham_y) -----------------------
    // score(p,t) = fma(-2bc_p, t, bc_p^2); d^2 = min_score + t^2
    float ma = BIGF, mb = BIGF, mc = BIGF, md = BIGF;
#pragma unroll 4
    for (int q = 0; q < P / 2; ++q) {
        float4 ef = s_ef4[q];  // broadcast, conflict-free
        ma = fminf(ma, fmaf(ef.y, t0, ef.x));
        mb = fminf(mb, fmaf(ef.w, t0, ef.z));
        mc = fminf(mc, fmaf(ef.y, t1, ef.x));
        md = fminf(md, fmaf(ef.w, t1, ef.z));
    }
    float d0 = fminf(ma, mb) + t0 * t0;
    float d1 = fminf(mc, md) + t1 * t1;
    float local = (v0 ? d0 : 0.0f) + (v1 ? d1 : 0.0f);
    unsigned cl = (unsigned)v0 + (unsigned)v1;

    // ---- phase 2: per-bin min over chunk targets (cham_x) -----------------
    // score(t,p) = fma(-2t, bc_p, t^2); d^2 = min_score + bc_p^2
    float b0 = BIGF, b1 = BIGF, b2 = BIGF, b3 = BIGF;
#pragma unroll 4
    for (int q = 0; q < CHUNK / 2; q += 2) {
        float4 a = s_gh4[q];
        float4 b = s_gh4[q + 1];
        b0 = fminf(b0, fmaf(a.x, bc, a.y));
        b1 = fminf(b1, fmaf(a.z, bc, a.w));
        b2 = fminf(b2, fmaf(b.x, bc, b.y));
        b3 = fminf(b3, fmaf(b.z, bc, b.w));
    }
    float bmin = fminf(fminf(b0, b1), fminf(b2, b3));
    float d2 = fmaxf(bmin + bc * bc, 0.0f);  // clamp fp rounding; keep >=0 for uint order
    atomicMin(&minbits[n * P + tid], __float_as_uint(d2));

    // ---- block-reduce cham_y partials -------------------------------------
    double locd = (double)local;
    for (int off = 32; off > 0; off >>= 1) {
        locd += __shfl_down(locd, off, 64);
        cl   += __shfl_down(cl, off, 64);
    }
    int wave = tid >> 6, lane = tid & 63;
    if (lane == 0) { s_wsum[wave] = locd; s_wcnt[wave] = cl; }
    __syncthreads();  // also drains this block's atomicMin (vmcnt at barrier)
    if (tid == 0) {
        double s = s_wsum[0] + s_wsum[1] + s_wsum[2] + s_wsum[3];
        unsigned cc = s_wcnt[0] + s_wcnt[1] + s_wcnt[2] + s_wcnt[3];
        atomicAdd(&ysum[n], s);
        atomicAdd(&ycnt[n], cc);
        __threadfence();
        unsigned old = __hip_atomic_fetch_add(done, 1u, __ATOMIC_ACQ_REL,
                                              __HIP_MEMORY_SCOPE_AGENT);
        s_last = (old == (unsigned)(gridDim.x * gridDim.y - 1));
    }
    __syncthreads();
    if (!s_last) return;

    // ---- last block: finalize ---------------------------------------------
    double part = 0.0;
    for (int nn = 0; nn < N; ++nn) {
        unsigned bbits = __hip_atomic_load(&minbits[nn * P + tid],
                                           __ATOMIC_RELAXED, __HIP_MEMORY_SCOPE_AGENT);
        part += (double)__uint_as_float(bbits);
    }
    for (int off = 32; off > 0; off >>= 1) part += __shfl_down(part, off, 64);
    if (lane == 0) s_wsum[wave] = part;
    __syncthreads();
    if (tid == 0) {
        double sx = (s_wsum[0] + s_wsum[1] + s_wsum[2] + s_wsum[3]) / (double)P;
        double sy = 0.0;
        for (int nn = 0; nn < N; ++nn) {
            double ys = __hip_atomic_load(&ysum[nn], __ATOMIC_RELAXED,
                                          __HIP_MEMORY_SCOPE_AGENT);
            unsigned yc = __hip_atomic_load(&ycnt[nn], __ATOMIC_RELAXED,
                                            __HIP_MEMORY_SCOPE_AGENT);
            sy += ys / (double)yc;
        }
        out[0] = (float)((sx + sy) / (double)N);
    }
}

extern "C" void kernel_launch(void* const* d_in, const int* in_sizes, int n_in,
                              void* d_out, int out_size, void* d_ws, size_t ws_size,
                              hipStream_t stream) {
    const float* bins = (const float*)d_in[0];
    const float* tgt  = (const float*)d_in[1];
    float* out = (float*)d_out;

    const int N = in_sizes[0] / (P + 1);  // 8
    const int M = in_sizes[1] / N;        // 65536

    char* ws = (char*)d_ws;
    unsigned* done    = (unsigned*)ws;
    double*   ysum    = (double*)(ws + 64);
    unsigned* ycnt    = (unsigned*)(ws + 128);
    unsigned* minbits = (unsigned*)(ws + 192);

    const int cps = (M + CHUNK - 1) / CHUNK;  // 128 chunks per sample

    hipLaunchKernelGGL(chamfer_init, dim3(1), dim3(BLOCK), 0, stream,
                       done, ysum, ycnt, minbits, N);
    hipLaunchKernelGGL(chamfer_main, dim3(cps, N), dim3(BLOCK), 0, stream,
                       bins, tgt, N, M, done, ysum, ycnt, minbits, out);
}